// Round 12
// baseline (254.130 us; speedup 1.0000x reference)
//
#include <hip/hip_runtime.h>
#include <math.h>

// Problem constants
static constexpr int B_  = 2;
static constexpr int T_  = 512;
static constexpr int S_  = 2048;
static constexpr int H_  = 768;
static constexpr int L_  = 32;
static constexpr int NH_ = 12;
static constexpr int HD_ = 64;   // H/NH
static constexpr int IM_ = 3072; // 4*H

typedef __bf16 bf16x8 __attribute__((ext_vector_type(8)));
typedef float  f32x4  __attribute__((ext_vector_type(4)));

__device__ __forceinline__ float bf2f(unsigned short u) {
    return __uint_as_float(((unsigned)u) << 16);
}
__device__ __forceinline__ unsigned short f2bf(float f) {
    unsigned u = __float_as_uint(f);
    u += 0x7fffu + ((u >> 16) & 1u);   // RNE
    return (unsigned short)(u >> 16);
}
__device__ __forceinline__ void gl_lds16(const void* g, void* l) {
    __builtin_amdgcn_global_load_lds((const __attribute__((address_space(1))) void*)g,
                                     (__attribute__((address_space(3))) void*)l, 16, 0, 0);
}

// ---------------------------------------------------------------------------
// k_q: q[i] = dq . Wq[i,:] + bq[i], one wave per row.
// Block 0 additionally normalizes span_masks (int32 vs packed-byte autodetect).
__global__ void k_q(const float* __restrict__ dq, const float* __restrict__ w,
                    const float* __restrict__ b, float* __restrict__ q,
                    const int* __restrict__ raw, int* __restrict__ mout) {
    int wv = threadIdx.x >> 6, lane = threadIdx.x & 63;
    int i = blockIdx.x * 4 + wv;
    const float* row = w + (size_t)i * H_;
    float acc = 0.f;
#pragma unroll
    for (int k = 0; k < 12; ++k) acc += dq[lane + 64 * k] * row[lane + 64 * k];
    for (int m = 32; m; m >>= 1) acc += __shfl_xor(acc, m, 64);
    if (lane == 0) q[i] = acc + b[i];
    if (blockIdx.x == 0) {
        __shared__ int bad;
        if (threadIdx.x == 0) bad = 0;
        __syncthreads();
        for (int t = threadIdx.x; t < 1024; t += 256) {
            int v = raw[t];
            if (v != 0 && v != 1) bad = 1;      // benign race
        }
        __syncthreads();
        int byte_layout = bad;
        const unsigned char* rb = (const unsigned char*)raw;
        for (int t = threadIdx.x; t < B_ * S_; t += 256)
            mout[t] = byte_layout ? (int)rb[t] : raw[t];
    }
}

// Fused: weight casts (blocks < CWB) + Wq_eff (blocks >= CWB).
static constexpr int CWB = 2880;   // = (2*H*H + 2*IM*H)/8/256
__global__ void k_castw(const float* __restrict__ s0, const float* __restrict__ s1,
                        const float* __restrict__ s2, const float* __restrict__ s3,
                        unsigned short* __restrict__ d0, unsigned short* __restrict__ d1,
                        unsigned short* __restrict__ d2, unsigned short* __restrict__ d3,
                        const float* __restrict__ q, const float* __restrict__ wk,
                        float* __restrict__ wq) {
    if (blockIdx.x >= CWB) {
        int i = (blockIdx.x - CWB) * 256 + threadIdx.x;   // 36*256 = 9216 exact
        int n = i / H_, hh = i % H_;
        float acc = 0.f;
        for (int d = 0; d < HD_; ++d)
            acc += q[n * HD_ + d] * wk[(size_t)(H_ + n * HD_ + d) * H_ + hh];
        wq[i] = acc;
        return;
    }
    const long n0 = (long)H_ * H_, n2 = (long)IM_ * H_;
    long gid = (long)(blockIdx.x * 256 + threadIdx.x) * 8;
    const float* s; unsigned short* d; long off;
    if (gid < n0)                { s = s0; d = d0; off = gid; }
    else if (gid < 2 * n0)       { s = s1; d = d1; off = gid - n0; }
    else if (gid < 2 * n0 + n2)  { s = s2; d = d2; off = gid - 2 * n0; }
    else                         { s = s3; d = d3; off = gid - 2 * n0 - n2; }
    float4 f0 = *(const float4*)(s + off);
    float4 f1 = *(const float4*)(s + off + 4);
    uint4 o;
    o.x = (unsigned)f2bf(f0.x) | ((unsigned)f2bf(f0.y) << 16);
    o.y = (unsigned)f2bf(f0.z) | ((unsigned)f2bf(f0.w) << 16);
    o.z = (unsigned)f2bf(f1.x) | ((unsigned)f2bf(f1.y) << 16);
    o.w = (unsigned)f2bf(f1.z) | ((unsigned)f2bf(f1.w) << 16);
    *(uint4*)(d + off) = o;
}

// Fused addpe + stok: one block per token row bt.
__global__ void k_xstok(const float* __restrict__ tr, const float* __restrict__ pe,
                        const float* __restrict__ wq,
                        unsigned short* __restrict__ xbf, float* __restrict__ stok) {
    __shared__ float sx[H_];
    int bt = blockIdx.x, tid = threadIdx.x;
    const float* trow = tr + (size_t)bt * H_;
    const float* prow = pe + (size_t)(bt % T_) * H_;
    if (tid < 192) {
        int h0 = tid * 4;
        float4 a = *(const float4*)(trow + h0);
        float4 p = *(const float4*)(prow + h0);
        float v0 = a.x + p.x, v1 = a.y + p.y, v2 = a.z + p.z, v3 = a.w + p.w;
        sx[h0] = v0; sx[h0 + 1] = v1; sx[h0 + 2] = v2; sx[h0 + 3] = v3;
        uint2 o;
        o.x = (unsigned)f2bf(v0) | ((unsigned)f2bf(v1) << 16);
        o.y = (unsigned)f2bf(v2) | ((unsigned)f2bf(v3) << 16);
        *(uint2*)(xbf + (size_t)bt * H_ + h0) = o;
    }
    __syncthreads();
    int lane = tid & 63, w = tid >> 6;
    float xv[12];
#pragma unroll
    for (int k = 0; k < 12; ++k) xv[k] = sx[lane + 64 * k];
#pragma unroll
    for (int hh = 0; hh < 3; ++hh) {
        int n = w * 3 + hh;
        const float* wr = wq + (size_t)n * H_;
        float acc = 0.f;
#pragma unroll
        for (int k = 0; k < 12; ++k) acc += xv[k] * wr[lane + 64 * k];
        for (int m = 32; m; m >>= 1) acc += __shfl_xor(acc, m, 64);
        if (lane == 0) stok[bt * NH_ + n] = acc;
    }
}

// sum of 4 bf16 partial buffers -> bf16, 8 elems/thread
__global__ void k_castv4(const unsigned short* __restrict__ p, size_t pstr,
                         unsigned short* __restrict__ dst, int n) {
    int i = (blockIdx.x * 256 + threadIdx.x) * 8;
    if (i >= n) return;
    float a[8] = {};
#pragma unroll
    for (int z = 0; z < 4; ++z) {
        uint4 u = *(const uint4*)(p + z * pstr + i);
        a[0] += bf2f((unsigned short)(u.x & 0xffff));
        a[1] += bf2f((unsigned short)(u.x >> 16));
        a[2] += bf2f((unsigned short)(u.y & 0xffff));
        a[3] += bf2f((unsigned short)(u.y >> 16));
        a[4] += bf2f((unsigned short)(u.z & 0xffff));
        a[5] += bf2f((unsigned short)(u.z >> 16));
        a[6] += bf2f((unsigned short)(u.w & 0xffff));
        a[7] += bf2f((unsigned short)(u.w >> 16));
    }
    uint4 o;
    o.x = (unsigned)f2bf(a[0]) | ((unsigned)f2bf(a[1]) << 16);
    o.y = (unsigned)f2bf(a[2]) | ((unsigned)f2bf(a[3]) << 16);
    o.z = (unsigned)f2bf(a[4]) | ((unsigned)f2bf(a[5]) << 16);
    o.w = (unsigned)f2bf(a[6]) | ((unsigned)f2bf(a[7]) << 16);
    *(uint4*)(dst + i) = o;
}

// ---------------------------------------------------------------------------
// bf16 MFMA GEMM v4: BARRIER-FREE wave-independent 64x64 tiles.
// Each wave computes one 64x64 output tile over kLen, staging its own
// 64 A-rows + 64 B-rows (BK=32, 8 KB private LDS slice, single-buffered):
//   wait vmcnt(0) -> ds_read 8x b128 -> wait lgkmcnt(0) -> issue next 8
//   global_load_lds -> 16 MFMA. vmcnt/lgkmcnt are per-wave; no LDS sharing
//   => ZERO s_barrier. 32 KB LDS/block -> 4-5 blocks/CU of free-running waves.
// Group decode (XCD-pinned): q=bid&7, k=bid>>3, g=q+8*(k/TB), xq=k%TB;
// y=g/SP, z=g%SP. Wave x-tile = xq*4+wid. All blocks of group g on XCD q =>
// the 64-row A band stays in that XCD's L2.
template <bool RELU, bool SPLIT>
__global__ __launch_bounds__(256)
void gemm_wv(const unsigned short* __restrict__ A, const unsigned short* __restrict__ W,
             const float* __restrict__ bias, unsigned short* __restrict__ Cout,
             int M, int N, int K, int kLen, int TB, int SP) {
    __shared__ unsigned short Ls[4 * 4096];   // 8 KB per wave
    const int tid = threadIdx.x, lane = tid & 63, wid = tid >> 6;
    const int q = blockIdx.x & 7, kb = blockIdx.x >> 3;
    const int g = q + 8 * (kb / TB), xq = kb % TB;
    const int y = SPLIT ? g / SP : g;
    const int z = SPLIT ? g - y * SP : 0;
    const int bm = y * 64, bn = (xq * 4 + wid) * 64;
    const int kOff = z * kLen;

    // staging addresses: lane -> r16 = lane>>2 (row in 16-group), c4 = lane&3.
    // store global chunk (c4 ^ ((r16>>1)&3)) at position c4 => 2-way-only
    // bank aliasing on the b128 fragment reads (same swizzle as R11, 0-conflict).
    const int r16 = lane >> 2, c4 = lane & 3;
    const int swc = (c4 ^ ((r16 >> 1) & 3)) * 8;
    const unsigned short* agp = A + (size_t)(bm + r16) * K + kOff + swc;
    const unsigned short* bgp = W + (size_t)(bn + r16) * K + kOff + swc;
    unsigned short* lA = Ls + wid * 4096;     // wave-private
    unsigned short* lB = lA + 2048;

    f32x4 acc[4][4];
#pragma unroll
    for (int i = 0; i < 4; ++i)
#pragma unroll
        for (int j = 0; j < 4; ++j) acc[i][j] = f32x4{0.f, 0.f, 0.f, 0.f};

    const int mrow = lane & 15;
    const int q4 = lane >> 4;
    const int sw = (q4 ^ ((mrow >> 1) & 3)) * 8;
    const int NIT = kLen >> 5;

    // prologue: stage tile 0 (8 x 1KB)
#pragma unroll
    for (int j = 0; j < 4; ++j) {
        gl_lds16(agp + (size_t)(16 * j) * K, lA + j * 512);
        gl_lds16(bgp + (size_t)(16 * j) * K, lB + j * 512);
    }
    for (int it = 0; it < NIT; ++it) {
        asm volatile("s_waitcnt vmcnt(0)" ::: "memory");   // tile staged (this wave)
        bf16x8 af[4], bfr[4];
#pragma unroll
        for (int i = 0; i < 4; ++i)
            af[i] = *(const bf16x8*)(lA + (i * 16 + mrow) * 32 + sw);
#pragma unroll
        for (int j = 0; j < 4; ++j)
            bfr[j] = *(const bf16x8*)(lB + (j * 16 + mrow) * 32 + sw);
        asm volatile("s_waitcnt lgkmcnt(0)" ::: "memory"); // frags in VGPRs
        if (it + 1 < NIT) {                                // refill (overlaps MFMA)
            const int k0 = (it + 1) << 5;
#pragma unroll
            for (int j = 0; j < 4; ++j) {
                gl_lds16(agp + (size_t)(16 * j) * K + k0, lA + j * 512);
                gl_lds16(bgp + (size_t)(16 * j) * K + k0, lB + j * 512);
            }
        }
#pragma unroll
        for (int i = 0; i < 4; ++i)
#pragma unroll
            for (int j = 0; j < 4; ++j)
                acc[i][j] = __builtin_amdgcn_mfma_f32_16x16x32_bf16(af[i], bfr[j], acc[i][j], 0, 0, 0);
    }

    // epilogue: C/D layout col=lane&15, row=(lane>>4)*4+reg (verified m89/m91)
    const bool addb = !SPLIT || z == 0;
    unsigned short* outp = SPLIT ? Cout + (size_t)z * M * N : Cout;
    const int lr = (lane >> 4) * 4, lc = lane & 15;
#pragma unroll
    for (int j = 0; j < 4; ++j) {
        int col = bn + j * 16 + lc;
        float bv = addb ? bias[col] : 0.f;
#pragma unroll
        for (int i = 0; i < 4; ++i) {
            int row0 = bm + i * 16 + lr;
#pragma unroll
            for (int r = 0; r < 4; ++r) {
                float v = acc[i][j][r] + bv;
                if (RELU) v = fmaxf(v, 0.f);
                outp[(size_t)(row0 + r) * N + col] = f2bf(v);
            }
        }
    }
}

// ---------------------------------------------------------------------------
// Per-span attention pooling
__global__ void k_attn(const float* __restrict__ stok, const unsigned short* __restrict__ vtok,
                       const int* __restrict__ span_ids, const int* __restrict__ masks,
                       unsigned short* __restrict__ ctx) {
    int r = blockIdx.x, b = r / S_;
    unsigned short* out = ctx + (size_t)r * H_;
    int tid = threadIdx.x;
    __shared__ float w[NH_][L_];
    __shared__ int idxs[L_];
    __shared__ int s_len;
    if (tid == 0) {
        int m = masks[r];
        int st = span_ids[2 * r], en = span_ids[2 * r + 1];
        int len = m ? (en - st) : 0;
        len = len < 0 ? 0 : (len > L_ ? L_ : len);
        s_len = len;
    }
    __syncthreads();
    int len = s_len;
    if (len == 0) {
        for (int h2 = tid; h2 < H_ / 2; h2 += 256) ((unsigned*)out)[h2] = 0u;
        return;
    }
    if (tid < L_) {
        int p = span_ids[2 * r] + tid;
        idxs[tid] = p < 0 ? 0 : (p > T_ - 1 ? T_ - 1 : p);
    }
    __syncthreads();
    for (int i = tid; i < NH_ * L_; i += 256) {
        int n = i / L_, l = i % L_;
        w[n][l] = (l < len) ? stok[(size_t)(b * T_ + idxs[l]) * NH_ + n] * 0.125f : -INFINITY;
    }
    __syncthreads();
    if (tid < NH_) {
        float mx = -INFINITY;
        for (int l = 0; l < len; ++l) mx = fmaxf(mx, w[tid][l]);
        float sum = 0.f;
        for (int l = 0; l < len; ++l) { float e = __expf(w[tid][l] - mx); w[tid][l] = e; sum += e; }
        float inv = 1.f / sum;
        for (int l = 0; l < len; ++l) w[tid][l] *= inv;
    }
    __syncthreads();
    if (tid < 192) {
        int h0 = tid * 4, n = h0 >> 6;
        float a0 = 0.f, a1 = 0.f, a2 = 0.f, a3 = 0.f;
        for (int l = 0; l < len; ++l) {
            float wl = w[n][l];
            const unsigned short* vr = vtok + (size_t)(b * T_ + idxs[l]) * H_ + h0;
            uint2 u = *(const uint2*)vr;
            a0 += wl * bf2f((unsigned short)(u.x & 0xffff));
            a1 += wl * bf2f((unsigned short)(u.x >> 16));
            a2 += wl * bf2f((unsigned short)(u.y & 0xffff));
            a3 += wl * bf2f((unsigned short)(u.y >> 16));
        }
        uint2 o;
        o.x = (unsigned)f2bf(a0) | ((unsigned)f2bf(a1) << 16);
        o.y = (unsigned)f2bf(a2) | ((unsigned)f2bf(a3) << 16);
        *(uint2*)(out + h0) = o;
    }
}

// ---------------------------------------------------------------------------
// LayerNorm over (sum of 4 bf16 partials + res).
template <bool RESROW, bool MASKOUT>
__global__ void k_ln(const unsigned short* __restrict__ parts, size_t pstr,
                     const float* __restrict__ resf, const unsigned short* __restrict__ resb,
                     const float* __restrict__ g, const float* __restrict__ bt,
                     float* __restrict__ outf, unsigned short* __restrict__ outb,
                     const int* __restrict__ masks) {
    int r = blockIdx.x;
    int tid = threadIdx.x;
    float v[3];
    float lsum = 0.f;
#pragma unroll
    for (int i = 0; i < 3; ++i) {
        int h = tid + 256 * i;
        float s = RESROW ? bf2f(resb[(size_t)r * H_ + h]) : resf[h];
#pragma unroll
        for (int z = 0; z < 4; ++z)
            s += bf2f(parts[z * pstr + (size_t)r * H_ + h]);
        v[i] = s;
        lsum += s;
    }
    __shared__ float sh[256];
    sh[tid] = lsum;
    __syncthreads();
    for (int st = 128; st > 0; st >>= 1) {
        if (tid < st) sh[tid] += sh[tid + st];
        __syncthreads();
    }
    float mean = sh[0] * (1.f / H_);
    __syncthreads();
    float lvar = 0.f;
#pragma unroll
    for (int i = 0; i < 3; ++i) { float d = v[i] - mean; lvar += d * d; }
    sh[tid] = lvar;
    __syncthreads();
    for (int st = 128; st > 0; st >>= 1) {
        if (tid < st) sh[tid] += sh[tid + st];
        __syncthreads();
    }
    float var = sh[0] * (1.f / H_);
    float scale = rsqrtf(var + 1e-5f);
    float mfac = 1.f;
    if (MASKOUT) mfac = masks[r] ? 1.f : 0.f;
#pragma unroll
    for (int i = 0; i < 3; ++i) {
        int h = tid + 256 * i;
        float o = ((v[i] - mean) * scale * g[h] + bt[h]) * mfac;
        if (MASKOUT) outf[(size_t)r * H_ + h] = o;
        else         outb[(size_t)r * H_ + h] = f2bf(o);
    }
}

// ---------------------------------------------------------------------------
extern "C" void kernel_launch(void* const* d_in, const int* in_sizes, int n_in,
                              void* d_out, int out_size, void* d_ws, size_t ws_size,
                              hipStream_t stream) {
    const float* token_reps = (const float*)d_in[0];
    const int*   span_ids   = (const int*)d_in[1];
    const int*   masks_raw  = (const int*)d_in[2];
    const float* pe   = (const float*)d_in[4];
    const float* dq   = (const float*)d_in[5];
    const float* in_w = (const float*)d_in[6];
    const float* in_b = (const float*)d_in[7];
    const float* ow   = (const float*)d_in[8];
    const float* ob   = (const float*)d_in[9];
    const float* g    = (const float*)d_in[10];
    const float* bt   = (const float*)d_in[11];
    const float* w1   = (const float*)d_in[12];
    const float* b1   = (const float*)d_in[13];
    const float* w2   = (const float*)d_in[14];
    const float* b2   = (const float*)d_in[15];

    const int BS = B_ * S_;        // 4096
    const int BT = B_ * T_;        // 1024

    // Workspace layout
    float* fws   = (float*)d_ws;
    float* stok  = fws;                         // 12288
    float* qv    = stok + BT * NH_;             // 768
    float* wqeff = qv + H_;                     // 9216
    unsigned short* us = (unsigned short*)(wqeff + NH_ * H_);
    unsigned short* pbuf = us;                       // 4 * BS*H
    unsigned short* xbf  = pbuf + (size_t)4 * BS * H_;
    unsigned short* vtok = xbf + (size_t)BT * H_;
    unsigned short* ctx  = vtok + (size_t)BT * H_;
    unsigned short* x1bf = ctx + (size_t)BS * H_;
    unsigned short* f1   = x1bf + (size_t)BS * H_;
    unsigned short* wvb  = f1 + (size_t)BS * IM_;
    unsigned short* owb  = wvb + H_ * H_;
    unsigned short* w1b  = owb + H_ * H_;
    unsigned short* w2b  = w1b + IM_ * H_;
    int* maskn = (int*)(w2b + H_ * IM_);

    // 1. q vector + mask normalize (fused)
    k_q<<<H_ / 4, 256, 0, stream>>>(dq, in_w, in_b, qv, masks_raw, maskn);
    // 2. weight casts + wqeff (fused)
    k_castw<<<CWB + 36, 256, 0, stream>>>(
        in_w + (size_t)2 * H_ * H_, ow, w1, w2, wvb, owb, w1b, w2b,
        qv, in_w, wqeff);
    // 3. x=tr+pe -> xbf + per-token scores (fused)
    k_xstok<<<BT, 256, 0, stream>>>(token_reps, pe, wqeff, xbf, stok);
    // 4. vtok partials (split-K x4): groups = 16y*4z = 64, TB=3 -> 192 blocks
    gemm_wv<false, true><<<192, 256, 0, stream>>>(
        xbf, wvb, in_b + 2 * H_, pbuf, BT, H_, H_, H_ / 4, 3, 4);
    k_castv4<<<(BT * H_ / 8 + 255) / 256, 256, 0, stream>>>(
        pbuf, (size_t)BT * H_, vtok, BT * H_);
    // 5. attention pooling -> ctx (bf16)
    k_attn<<<BS, 256, 0, stream>>>(stok, vtok, span_ids, maskn, ctx);
    // 6. out_proj partials (split-K x4): groups = 64y*4z = 256, TB=3 -> 768
    gemm_wv<false, true><<<768, 256, 0, stream>>>(
        ctx, owb, ob, pbuf, BS, H_, H_, H_ / 4, 3, 4);
    // 7. x1bf = bf16(LN(sum(partials) + dq))
    k_ln<false, false><<<BS, 256, 0, stream>>>(
        pbuf, (size_t)BS * H_, dq, nullptr, g, bt, nullptr, x1bf, nullptr);
    // 8. f1 = bf16(relu(x1 @ w1^T + b1)): groups = 64y, TB=12 -> 768 blocks
    gemm_wv<true, false><<<768, 256, 0, stream>>>(
        x1bf, w1b, b1, f1, BS, IM_, H_, H_, 12, 1);
    // 9. FFN2 partials (split-K x4): groups = 64y*4z = 256, TB=3 -> 768
    gemm_wv<false, true><<<768, 256, 0, stream>>>(
        f1, w2b, b2, pbuf, BS, H_, IM_, IM_ / 4, 3, 4);
    // 10. out = LN(sum(partials) + x1) * mask
    k_ln<true, true><<<BS, 256, 0, stream>>>(
        pbuf, (size_t)BS * H_, nullptr, x1bf, g, bt, (float*)d_out, nullptr, maskn);
}

// Round 13
// 240.685 us; speedup vs baseline: 1.0559x; 1.0559x over previous
//
#include <hip/hip_runtime.h>
#include <math.h>

// Problem constants
static constexpr int B_  = 2;
static constexpr int T_  = 512;
static constexpr int S_  = 2048;
static constexpr int H_  = 768;
static constexpr int L_  = 32;
static constexpr int NH_ = 12;
static constexpr int HD_ = 64;   // H/NH
static constexpr int IM_ = 3072; // 4*H

typedef __bf16 bf16x8 __attribute__((ext_vector_type(8)));
typedef float  f32x4  __attribute__((ext_vector_type(4)));

__device__ __forceinline__ float bf2f(unsigned short u) {
    return __uint_as_float(((unsigned)u) << 16);
}
__device__ __forceinline__ unsigned short f2bf(float f) {
    unsigned u = __float_as_uint(f);
    u += 0x7fffu + ((u >> 16) & 1u);   // RNE
    return (unsigned short)(u >> 16);
}
__device__ __forceinline__ void gl_lds16(const void* g, void* l) {
    __builtin_amdgcn_global_load_lds((const __attribute__((address_space(1))) void*)g,
                                     (__attribute__((address_space(3))) void*)l, 16, 0, 0);
}

// ---------------------------------------------------------------------------
// k_q: q[i] = dq . Wq[i,:] + bq[i], one wave per row.
// Block 0 additionally normalizes span_masks (int32 vs packed-byte autodetect).
__global__ void k_q(const float* __restrict__ dq, const float* __restrict__ w,
                    const float* __restrict__ b, float* __restrict__ q,
                    const int* __restrict__ raw, int* __restrict__ mout) {
    int wv = threadIdx.x >> 6, lane = threadIdx.x & 63;
    int i = blockIdx.x * 4 + wv;
    const float* row = w + (size_t)i * H_;
    float acc = 0.f;
#pragma unroll
    for (int k = 0; k < 12; ++k) acc += dq[lane + 64 * k] * row[lane + 64 * k];
    for (int m = 32; m; m >>= 1) acc += __shfl_xor(acc, m, 64);
    if (lane == 0) q[i] = acc + b[i];
    if (blockIdx.x == 0) {
        __shared__ int bad;
        if (threadIdx.x == 0) bad = 0;
        __syncthreads();
        for (int t = threadIdx.x; t < 1024; t += 256) {
            int v = raw[t];
            if (v != 0 && v != 1) bad = 1;      // benign race
        }
        __syncthreads();
        int byte_layout = bad;
        const unsigned char* rb = (const unsigned char*)raw;
        for (int t = threadIdx.x; t < B_ * S_; t += 256)
            mout[t] = byte_layout ? (int)rb[t] : raw[t];
    }
}

// Fused: weight casts (blocks < CWB) + Wq_eff (blocks >= CWB).
static constexpr int CWB = 2880;   // = (2*H*H + 2*IM*H)/8/256
__global__ void k_castw(const float* __restrict__ s0, const float* __restrict__ s1,
                        const float* __restrict__ s2, const float* __restrict__ s3,
                        unsigned short* __restrict__ d0, unsigned short* __restrict__ d1,
                        unsigned short* __restrict__ d2, unsigned short* __restrict__ d3,
                        const float* __restrict__ q, const float* __restrict__ wk,
                        float* __restrict__ wq) {
    if (blockIdx.x >= CWB) {
        int i = (blockIdx.x - CWB) * 256 + threadIdx.x;   // 36*256 = 9216 exact
        int n = i / H_, hh = i % H_;
        float acc = 0.f;
        for (int d = 0; d < HD_; ++d)
            acc += q[n * HD_ + d] * wk[(size_t)(H_ + n * HD_ + d) * H_ + hh];
        wq[i] = acc;
        return;
    }
    const long n0 = (long)H_ * H_, n2 = (long)IM_ * H_;
    long gid = (long)(blockIdx.x * 256 + threadIdx.x) * 8;
    const float* s; unsigned short* d; long off;
    if (gid < n0)                { s = s0; d = d0; off = gid; }
    else if (gid < 2 * n0)       { s = s1; d = d1; off = gid - n0; }
    else if (gid < 2 * n0 + n2)  { s = s2; d = d2; off = gid - 2 * n0; }
    else                         { s = s3; d = d3; off = gid - 2 * n0 - n2; }
    float4 f0 = *(const float4*)(s + off);
    float4 f1 = *(const float4*)(s + off + 4);
    uint4 o;
    o.x = (unsigned)f2bf(f0.x) | ((unsigned)f2bf(f0.y) << 16);
    o.y = (unsigned)f2bf(f0.z) | ((unsigned)f2bf(f0.w) << 16);
    o.z = (unsigned)f2bf(f1.x) | ((unsigned)f2bf(f1.y) << 16);
    o.w = (unsigned)f2bf(f1.z) | ((unsigned)f2bf(f1.w) << 16);
    *(uint4*)(d + off) = o;
}

// Fused addpe + stok: one block per token row bt.
__global__ void k_xstok(const float* __restrict__ tr, const float* __restrict__ pe,
                        const float* __restrict__ wq,
                        unsigned short* __restrict__ xbf, float* __restrict__ stok) {
    __shared__ float sx[H_];
    int bt = blockIdx.x, tid = threadIdx.x;
    const float* trow = tr + (size_t)bt * H_;
    const float* prow = pe + (size_t)(bt % T_) * H_;
    if (tid < 192) {
        int h0 = tid * 4;
        float4 a = *(const float4*)(trow + h0);
        float4 p = *(const float4*)(prow + h0);
        float v0 = a.x + p.x, v1 = a.y + p.y, v2 = a.z + p.z, v3 = a.w + p.w;
        sx[h0] = v0; sx[h0 + 1] = v1; sx[h0 + 2] = v2; sx[h0 + 3] = v3;
        uint2 o;
        o.x = (unsigned)f2bf(v0) | ((unsigned)f2bf(v1) << 16);
        o.y = (unsigned)f2bf(v2) | ((unsigned)f2bf(v3) << 16);
        *(uint2*)(xbf + (size_t)bt * H_ + h0) = o;
    }
    __syncthreads();
    int lane = tid & 63, w = tid >> 6;
    float xv[12];
#pragma unroll
    for (int k = 0; k < 12; ++k) xv[k] = sx[lane + 64 * k];
#pragma unroll
    for (int hh = 0; hh < 3; ++hh) {
        int n = w * 3 + hh;
        const float* wr = wq + (size_t)n * H_;
        float acc = 0.f;
#pragma unroll
        for (int k = 0; k < 12; ++k) acc += xv[k] * wr[lane + 64 * k];
        for (int m = 32; m; m >>= 1) acc += __shfl_xor(acc, m, 64);
        if (lane == 0) stok[bt * NH_ + n] = acc;
    }
}

// sum of 4 bf16 partial buffers -> bf16, 8 elems/thread
__global__ void k_castv4(const unsigned short* __restrict__ p, size_t pstr,
                         unsigned short* __restrict__ dst, int n) {
    int i = (blockIdx.x * 256 + threadIdx.x) * 8;
    if (i >= n) return;
    float a[8] = {};
#pragma unroll
    for (int z = 0; z < 4; ++z) {
        uint4 u = *(const uint4*)(p + z * pstr + i);
        a[0] += bf2f((unsigned short)(u.x & 0xffff));
        a[1] += bf2f((unsigned short)(u.x >> 16));
        a[2] += bf2f((unsigned short)(u.y & 0xffff));
        a[3] += bf2f((unsigned short)(u.y >> 16));
        a[4] += bf2f((unsigned short)(u.z & 0xffff));
        a[5] += bf2f((unsigned short)(u.z >> 16));
        a[6] += bf2f((unsigned short)(u.w & 0xffff));
        a[7] += bf2f((unsigned short)(u.w >> 16));
    }
    uint4 o;
    o.x = (unsigned)f2bf(a[0]) | ((unsigned)f2bf(a[1]) << 16);
    o.y = (unsigned)f2bf(a[2]) | ((unsigned)f2bf(a[3]) << 16);
    o.z = (unsigned)f2bf(a[4]) | ((unsigned)f2bf(a[5]) << 16);
    o.w = (unsigned)f2bf(a[6]) | ((unsigned)f2bf(a[7]) << 16);
    *(uint4*)(dst + i) = o;
}

// ---------------------------------------------------------------------------
// bf16 MFMA GEMM (R11 core — best measured): shared staging, BK=32, 16 KB
// total LDS (~5 blocks/CU), buffer-split-K with bf16 partials, XCD-pinned
// swizzle. 128x128 tile, 256 thr = 4 waves, wave 64x64 = 4x4 MFMA 16x16x32.
// 64B LDS rows: XOR swizzle chunk ^= (row>>1)&3 => exactly 2-way bank
// aliasing on ds_read_b128 (free, m136; measured 0 conflicts).
// Rationale vs R12's wave-private variant: shared staging has 2.6x less LDS
// traffic per FLOP; barrier cost is absorbed by 3-5 co-resident blocks (m114).
template <bool RELU, bool SPLIT>
__global__ __launch_bounds__(256)
void gemm_bt(const unsigned short* __restrict__ A, const unsigned short* __restrict__ W,
             const float* __restrict__ bias, unsigned short* __restrict__ Cout,
             int M, int N, int K, int kLen, int TX, int SP) {
    __shared__ unsigned short As[4096];    // 128 rows x 32 cols bf16 = 8 KB
    __shared__ unsigned short Bs[4096];
    // XCD-pinned block swizzle: all TX x-tiles of a (y,z) group on one XCD
    const int qx = blockIdx.x & 7, t = blockIdx.x >> 3;
    const int gi = t / TX, x = t - gi * TX;
    const int g = gi * 8 + qx;
    int y, z;
    if (SPLIT) { y = g / SP; z = g - y * SP; } else { y = g; z = 0; }
    const int bm = y * 128, bn = x * 128;
    const int kOff = z * kLen;

    const int tid = threadIdx.x, lane = tid & 63, wid = tid >> 6;   // 0..3
    const int wm = (wid >> 1) * 64, wn = (wid & 1) * 64;
    // staging: wave w stages rows [32w,32w+32) of A and B (2x 1KB each).
    const int r16 = lane >> 2, c4 = lane & 3;
    const int swc = (c4 ^ ((r16 >> 1) & 3)) * 8;       // element offset in row
    const unsigned short* agp = A + (size_t)(bm + wid * 32 + r16) * K + kOff + swc;
    const unsigned short* bgp = W + (size_t)(bn + wid * 32 + r16) * K + kOff + swc;
    unsigned short* lA = As + wid * 1024;              // wave-uniform bases
    unsigned short* lB = Bs + wid * 1024;

    f32x4 acc[4][4];
#pragma unroll
    for (int i = 0; i < 4; ++i)
#pragma unroll
        for (int j = 0; j < 4; ++j) acc[i][j] = f32x4{0.f, 0.f, 0.f, 0.f};

    const int mrow = lane & 15;
    const int q4 = lane >> 4;                          // frag chunk 0..3
    const int sw = (q4 ^ ((mrow >> 1) & 3)) * 8;       // same for all i/j tiles
    const int NIT = kLen >> 5;

    for (int it = 0; it < NIT; ++it) {
        const int k0 = it << 5;
        gl_lds16(agp + k0, lA);
        gl_lds16(agp + (size_t)16 * K + k0, lA + 512);
        gl_lds16(bgp + k0, lB);
        gl_lds16(bgp + (size_t)16 * K + k0, lB + 512);
        __syncthreads();                   // drains vmcnt: tile staged
        bf16x8 af[4], bfr[4];
#pragma unroll
        for (int i = 0; i < 4; ++i)
            af[i] = *(const bf16x8*)(As + (wm + i * 16 + mrow) * 32 + sw);
#pragma unroll
        for (int j = 0; j < 4; ++j)
            bfr[j] = *(const bf16x8*)(Bs + (wn + j * 16 + mrow) * 32 + sw);
#pragma unroll
        for (int i = 0; i < 4; ++i)
#pragma unroll
            for (int j = 0; j < 4; ++j)
                acc[i][j] = __builtin_amdgcn_mfma_f32_16x16x32_bf16(af[i], bfr[j], acc[i][j], 0, 0, 0);
        __syncthreads();                   // all waves done reading
    }

    // epilogue: C/D layout col=lane&15, row=(lane>>4)*4+reg (verified m89/m91)
    const bool addb = !SPLIT || z == 0;
    unsigned short* outp = SPLIT ? Cout + (size_t)z * M * N : Cout;
    const int lr = (lane >> 4) * 4, lc = lane & 15;
#pragma unroll
    for (int j = 0; j < 4; ++j) {
        int col = bn + wn + j * 16 + lc;
        float bv = addb ? bias[col] : 0.f;
#pragma unroll
        for (int i = 0; i < 4; ++i) {
            int row0 = bm + wm + i * 16 + lr;
#pragma unroll
            for (int r = 0; r < 4; ++r) {
                float v = acc[i][j][r] + bv;
                if (RELU) v = fmaxf(v, 0.f);
                outp[(size_t)(row0 + r) * N + col] = f2bf(v);
            }
        }
    }
}

// ---------------------------------------------------------------------------
// Per-span attention pooling
__global__ void k_attn(const float* __restrict__ stok, const unsigned short* __restrict__ vtok,
                       const int* __restrict__ span_ids, const int* __restrict__ masks,
                       unsigned short* __restrict__ ctx) {
    int r = blockIdx.x, b = r / S_;
    unsigned short* out = ctx + (size_t)r * H_;
    int tid = threadIdx.x;
    __shared__ float w[NH_][L_];
    __shared__ int idxs[L_];
    __shared__ int s_len;
    if (tid == 0) {
        int m = masks[r];
        int st = span_ids[2 * r], en = span_ids[2 * r + 1];
        int len = m ? (en - st) : 0;
        len = len < 0 ? 0 : (len > L_ ? L_ : len);
        s_len = len;
    }
    __syncthreads();
    int len = s_len;
    if (len == 0) {
        for (int h2 = tid; h2 < H_ / 2; h2 += 256) ((unsigned*)out)[h2] = 0u;
        return;
    }
    if (tid < L_) {
        int p = span_ids[2 * r] + tid;
        idxs[tid] = p < 0 ? 0 : (p > T_ - 1 ? T_ - 1 : p);
    }
    __syncthreads();
    for (int i = tid; i < NH_ * L_; i += 256) {
        int n = i / L_, l = i % L_;
        w[n][l] = (l < len) ? stok[(size_t)(b * T_ + idxs[l]) * NH_ + n] * 0.125f : -INFINITY;
    }
    __syncthreads();
    if (tid < NH_) {
        float mx = -INFINITY;
        for (int l = 0; l < len; ++l) mx = fmaxf(mx, w[tid][l]);
        float sum = 0.f;
        for (int l = 0; l < len; ++l) { float e = __expf(w[tid][l] - mx); w[tid][l] = e; sum += e; }
        float inv = 1.f / sum;
        for (int l = 0; l < len; ++l) w[tid][l] *= inv;
    }
    __syncthreads();
    if (tid < 192) {
        int h0 = tid * 4, n = h0 >> 6;
        float a0 = 0.f, a1 = 0.f, a2 = 0.f, a3 = 0.f;
        for (int l = 0; l < len; ++l) {
            float wl = w[n][l];
            const unsigned short* vr = vtok + (size_t)(b * T_ + idxs[l]) * H_ + h0;
            uint2 u = *(const uint2*)vr;
            a0 += wl * bf2f((unsigned short)(u.x & 0xffff));
            a1 += wl * bf2f((unsigned short)(u.x >> 16));
            a2 += wl * bf2f((unsigned short)(u.y & 0xffff));
            a3 += wl * bf2f((unsigned short)(u.y >> 16));
        }
        uint2 o;
        o.x = (unsigned)f2bf(a0) | ((unsigned)f2bf(a1) << 16);
        o.y = (unsigned)f2bf(a2) | ((unsigned)f2bf(a3) << 16);
        *(uint2*)(out + h0) = o;
    }
}

// ---------------------------------------------------------------------------
// LayerNorm over (sum of 4 bf16 partials + res).
template <bool RESROW, bool MASKOUT>
__global__ void k_ln(const unsigned short* __restrict__ parts, size_t pstr,
                     const float* __restrict__ resf, const unsigned short* __restrict__ resb,
                     const float* __restrict__ g, const float* __restrict__ bt,
                     float* __restrict__ outf, unsigned short* __restrict__ outb,
                     const int* __restrict__ masks) {
    int r = blockIdx.x;
    int tid = threadIdx.x;
    float v[3];
    float lsum = 0.f;
#pragma unroll
    for (int i = 0; i < 3; ++i) {
        int h = tid + 256 * i;
        float s = RESROW ? bf2f(resb[(size_t)r * H_ + h]) : resf[h];
#pragma unroll
        for (int z = 0; z < 4; ++z)
            s += bf2f(parts[z * pstr + (size_t)r * H_ + h]);
        v[i] = s;
        lsum += s;
    }
    __shared__ float sh[256];
    sh[tid] = lsum;
    __syncthreads();
    for (int st = 128; st > 0; st >>= 1) {
        if (tid < st) sh[tid] += sh[tid + st];
        __syncthreads();
    }
    float mean = sh[0] * (1.f / H_);
    __syncthreads();
    float lvar = 0.f;
#pragma unroll
    for (int i = 0; i < 3; ++i) { float d = v[i] - mean; lvar += d * d; }
    sh[tid] = lvar;
    __syncthreads();
    for (int st = 128; st > 0; st >>= 1) {
        if (tid < st) sh[tid] += sh[tid + st];
        __syncthreads();
    }
    float var = sh[0] * (1.f / H_);
    float scale = rsqrtf(var + 1e-5f);
    float mfac = 1.f;
    if (MASKOUT) mfac = masks[r] ? 1.f : 0.f;
#pragma unroll
    for (int i = 0; i < 3; ++i) {
        int h = tid + 256 * i;
        float o = ((v[i] - mean) * scale * g[h] + bt[h]) * mfac;
        if (MASKOUT) outf[(size_t)r * H_ + h] = o;
        else         outb[(size_t)r * H_ + h] = f2bf(o);
    }
}

// ---------------------------------------------------------------------------
extern "C" void kernel_launch(void* const* d_in, const int* in_sizes, int n_in,
                              void* d_out, int out_size, void* d_ws, size_t ws_size,
                              hipStream_t stream) {
    const float* token_reps = (const float*)d_in[0];
    const int*   span_ids   = (const int*)d_in[1];
    const int*   masks_raw  = (const int*)d_in[2];
    const float* pe   = (const float*)d_in[4];
    const float* dq   = (const float*)d_in[5];
    const float* in_w = (const float*)d_in[6];
    const float* in_b = (const float*)d_in[7];
    const float* ow   = (const float*)d_in[8];
    const float* ob   = (const float*)d_in[9];
    const float* g    = (const float*)d_in[10];
    const float* bt   = (const float*)d_in[11];
    const float* w1   = (const float*)d_in[12];
    const float* b1   = (const float*)d_in[13];
    const float* w2   = (const float*)d_in[14];
    const float* b2   = (const float*)d_in[15];

    const int BS = B_ * S_;        // 4096
    const int BT = B_ * T_;        // 1024

    // Workspace layout
    float* fws   = (float*)d_ws;
    float* stok  = fws;                         // 12288
    float* qv    = stok + BT * NH_;             // 768
    float* wqeff = qv + H_;                     // 9216
    unsigned short* us = (unsigned short*)(wqeff + NH_ * H_);
    unsigned short* pbuf = us;                       // 4 * BS*H
    unsigned short* xbf  = pbuf + (size_t)4 * BS * H_;
    unsigned short* vtok = xbf + (size_t)BT * H_;
    unsigned short* ctx  = vtok + (size_t)BT * H_;
    unsigned short* x1bf = ctx + (size_t)BS * H_;
    unsigned short* f1   = x1bf + (size_t)BS * H_;
    unsigned short* wvb  = f1 + (size_t)BS * IM_;
    unsigned short* owb  = wvb + H_ * H_;
    unsigned short* w1b  = owb + H_ * H_;
    unsigned short* w2b  = w1b + IM_ * H_;
    int* maskn = (int*)(w2b + H_ * IM_);

    // 1. q vector + mask normalize (fused)
    k_q<<<H_ / 4, 256, 0, stream>>>(dq, in_w, in_b, qv, masks_raw, maskn);
    // 2. weight casts + wqeff (fused)
    k_castw<<<CWB + 36, 256, 0, stream>>>(
        in_w + (size_t)2 * H_ * H_, ow, w1, w2, wvb, owb, w1b, w2b,
        qv, in_w, wqeff);
    // 3. x=tr+pe -> xbf + per-token scores (fused)
    k_xstok<<<BT, 256, 0, stream>>>(token_reps, pe, wqeff, xbf, stok);
    // 4. vtok partials (split-K x4, bf16) -> sum-cast
    gemm_bt<false, true><<<192, 256, 0, stream>>>(
        xbf, wvb, in_b + 2 * H_, pbuf, BT, H_, H_, H_ / 4, 6, 4);
    k_castv4<<<(BT * H_ / 8 + 255) / 256, 256, 0, stream>>>(
        pbuf, (size_t)BT * H_, vtok, BT * H_);
    // 5. attention pooling -> ctx (bf16)
    k_attn<<<BS, 256, 0, stream>>>(stok, vtok, span_ids, maskn, ctx);
    // 6. out_proj partials (split-K x4): 768 blocks
    gemm_bt<false, true><<<768, 256, 0, stream>>>(
        ctx, owb, ob, pbuf, BS, H_, H_, H_ / 4, 6, 4);
    // 7. x1bf = bf16(LN(sum(partials) + dq))
    k_ln<false, false><<<BS, 256, 0, stream>>>(
        pbuf, (size_t)BS * H_, dq, nullptr, g, bt, nullptr, x1bf, nullptr);
    // 8. f1 = bf16(relu(x1 @ w1^T + b1)): 768 blocks
    gemm_bt<true, false><<<768, 256, 0, stream>>>(
        x1bf, w1b, b1, f1, BS, IM_, H_, H_, 24, 1);
    // 9. FFN2 partials (split-K x4): 768 blocks
    gemm_bt<false, true><<<768, 256, 0, stream>>>(
        f1, w2b, b2, pbuf, BS, H_, IM_, IM_ / 4, 6, 4);
    // 10. out = LN(sum(partials) + x1) * mask
    k_ln<true, true><<<BS, 256, 0, stream>>>(
        pbuf, (size_t)BS * H_, nullptr, x1bf, g, bt, (float*)d_out, nullptr, maskn);
}